// Round 3
// baseline (83.513 us; speedup 1.0000x reference)
//
#include <hip/hip_runtime.h>
#include <math.h>

// KShape dists via bf16 MFMA. B=256, K=16, SZ=512, D=8.
// corr[b,i,k] = sum_{t,d} xpad[b][(i+t)*8+d] * c[k][t*8+d],  i in [0,1022] (lag s=i-511)
// dists[b,k] = max_i corr / (||x_b|| * k); k=0 -> 0. labels = first argmax.
// out: [0..255]=labels(float), [256..4351]=dists.
//
// R3: 8 row-tiles/wave via 32-slot A-fragment ring (1 ds_read_b128 -> 8 MFMAs),
// halves per-wave B-L2 refetch vs R2; B prefetch depth 4 to cover ~200cy L2 latency.

#define NB 256
#define NK 16
#define NS 512
#define ND 8
#define BAND 1040   // xq rows: max read row = 128*3 + 4*159 + 15 + 3 = 1038

typedef __bf16 bf16x8 __attribute__((ext_vector_type(8)));
typedef float floatx4 __attribute__((ext_vector_type(4)));

// ---- pack centers into B-fragment order ----
// Bpk[kc*64 + L][0..8) = bf16( c[n = L&15][ (kc*4 + (L>>4))*8 + j ] )  j=0..7
__global__ void pack_kernel(const float* __restrict__ c, __bf16* __restrict__ bpk)
{
    int kc = blockIdx.x;      // 0..127 chunk of 32 contraction elems
    int L  = threadIdx.x;     // 0..63
    int n = L & 15, quad = L >> 4;
    const float4* src = (const float4*)(c + ((size_t)n * NS + (size_t)(kc * 4 + quad)) * ND);
    float4 a = src[0], b = src[1];
    bf16x8 v;
    v[0] = (__bf16)a.x; v[1] = (__bf16)a.y; v[2] = (__bf16)a.z; v[3] = (__bf16)a.w;
    v[4] = (__bf16)b.x; v[5] = (__bf16)b.y; v[6] = (__bf16)b.z; v[7] = (__bf16)b.w;
    *(bf16x8*)(bpk + ((size_t)kc * 64 + L) * 8) = v;
}

// ---- main: one block = (b, half h of the 1024 lag rows); 4 waves x 8 row-tiles ----
__global__ __launch_bounds__(256, 2) void dists_mfma(
    const float* __restrict__ x, const __bf16* __restrict__ bpk, float* __restrict__ wsf)
{
    __shared__ __align__(16) __bf16 xq[BAND * 8];   // 16.25 KB
    __shared__ float wred[4][16];

    const int tid = threadIdx.x;
    const int b   = blockIdx.x;
    const int h   = blockIdx.y;
    const int m0  = h * 512;

    // stage band: global padded row j = m0 + jj; x support is j in [511,1023)
    for (int jj = tid; jj < BAND; jj += 256) {
        int j = m0 + jj;
        bf16x8 v;
        if (j >= 511 && j < 1023) {
            const float4* p = (const float4*)(x + ((size_t)b * NS + (size_t)(j - 511)) * ND);
            float4 a = p[0], bb = p[1];
            v[0] = (__bf16)a.x;  v[1] = (__bf16)a.y;  v[2] = (__bf16)a.z;  v[3] = (__bf16)a.w;
            v[4] = (__bf16)bb.x; v[5] = (__bf16)bb.y; v[6] = (__bf16)bb.z; v[7] = (__bf16)bb.w;
        } else {
            #pragma unroll
            for (int e = 0; e < 8; ++e) v[e] = (__bf16)0.0f;
        }
        *(bf16x8*)(xq + (size_t)jj * 8) = v;
    }
    __syncthreads();

    const int L    = tid & 63;
    const int w    = tid >> 6;     // wave id: local rows [128w, 128w+128), tiles rt=0..7
    const int m    = L & 15;       // A row within tile / D col (center id)
    const int quad = L >> 4;

    // A-frag for (rt, kc): 16B at gb + 8*(16rt + 4kc)
    const __bf16* gb = xq + 8 * (128 * w + m + quad);
    const bf16x8* Bp = (const bf16x8*)bpk;

    // ring: Q[(kc + 4rt) & 31] = frag(rt, kc). Init slots = row4 0..31.
    bf16x8 Q[32];
    #pragma unroll
    for (int i = 0; i < 32; ++i) Q[i] = *(const bf16x8*)(gb + 32 * i);

    // B prefetch pipeline, depth 4
    bf16x8 Bv[4];
    #pragma unroll
    for (int i = 0; i < 4; ++i) Bv[i] = Bp[(size_t)i * 64 + L];

    floatx4 acc[8] = {};

    for (int kc0 = 0; kc0 < 128; kc0 += 32) {
        #pragma unroll
        for (int s = 0; s < 32; ++s) {
            const int kc = kc0 + s;
            bf16x8 bcur = Bv[s & 3];
            acc[0] = __builtin_amdgcn_mfma_f32_16x16x32_bf16(Q[(s + 0)  & 31], bcur, acc[0], 0, 0, 0);
            acc[1] = __builtin_amdgcn_mfma_f32_16x16x32_bf16(Q[(s + 4)  & 31], bcur, acc[1], 0, 0, 0);
            acc[2] = __builtin_amdgcn_mfma_f32_16x16x32_bf16(Q[(s + 8)  & 31], bcur, acc[2], 0, 0, 0);
            acc[3] = __builtin_amdgcn_mfma_f32_16x16x32_bf16(Q[(s + 12) & 31], bcur, acc[3], 0, 0, 0);
            acc[4] = __builtin_amdgcn_mfma_f32_16x16x32_bf16(Q[(s + 16) & 31], bcur, acc[4], 0, 0, 0);
            acc[5] = __builtin_amdgcn_mfma_f32_16x16x32_bf16(Q[(s + 20) & 31], bcur, acc[5], 0, 0, 0);
            acc[6] = __builtin_amdgcn_mfma_f32_16x16x32_bf16(Q[(s + 24) & 31], bcur, acc[6], 0, 0, 0);
            acc[7] = __builtin_amdgcn_mfma_f32_16x16x32_bf16(Q[(s + 28) & 31], bcur, acc[7], 0, 0, 0);
            // slot s is dead after rt=0 use at this iter; refill with row4 = kc+32
            Q[s & 31] = *(const bf16x8*)(gb + 8 * (4 * kc + 128));
            Bv[s & 3] = Bp[(size_t)((kc + 4) & 127) * 64 + L];
        }
    }

    // D layout: col = lane&15 (center), row-in-tile = quad*4 + e.
    // global lag row = 512h + 128w + 16rt + 4quad + e; phantom row 1023 excluded.
    float vmax = -INFINITY;
    #pragma unroll
    for (int r = 0; r < 8; ++r) {
        #pragma unroll
        for (int e = 0; e < 4; ++e) {
            bool phantom = (h == 1) & (w == 3) & (r == 7) & (quad == 3) & (e == 3);
            vmax = fmaxf(vmax, phantom ? -INFINITY : acc[r][e]);
        }
    }
    vmax = fmaxf(vmax, __shfl_xor(vmax, 16));
    vmax = fmaxf(vmax, __shfl_xor(vmax, 32));
    if (quad == 0) wred[w][m] = vmax;
    __syncthreads();
    if (tid < 16) {
        float mm = fmaxf(fmaxf(wred[0][tid], wred[1][tid]),
                         fmaxf(wred[2][tid], wred[3][tid]));
        wsf[((size_t)b * 2 + h) * 16 + tid] = mm;
    }
}

// ---- finalize: norm, scale, dists, labels ----
__global__ void finalize(const float* __restrict__ x, const float* __restrict__ wsf,
                         float* __restrict__ out)
{
    __shared__ float redn[4];
    __shared__ float dd[16];
    const int b = blockIdx.x, tid = threadIdx.x;
    const float4* x4 = (const float4*)(x + (size_t)b * (NS * ND));
    float ss = 0.f;
    #pragma unroll
    for (int i = 0; i < 4; ++i) {
        float4 v = x4[tid + 256 * i];
        ss += v.x * v.x + v.y * v.y + v.z * v.z + v.w * v.w;
    }
    #pragma unroll
    for (int off = 32; off; off >>= 1) ss += __shfl_down(ss, off);
    if ((tid & 63) == 0) redn[tid >> 6] = ss;
    __syncthreads();
    float nrm = sqrtf(redn[0] + redn[1] + redn[2] + redn[3]);
    if (tid < 16) {
        float mm = fmaxf(wsf[(size_t)b * 32 + tid], wsf[(size_t)b * 32 + 16 + tid]);
        float denom = nrm * (float)tid;
        float d = (denom < 1e-9f) ? 0.f : mm / denom;
        dd[tid] = d;
        out[NB + b * NK + tid] = d;
    }
    __syncthreads();
    if (tid == 0) {
        float best = dd[0]; int lab = 0;
        #pragma unroll
        for (int k = 1; k < NK; ++k) if (dd[k] > best) { best = dd[k]; lab = k; }
        out[b] = (float)lab;
    }
}

extern "C" void kernel_launch(void* const* d_in, const int* in_sizes, int n_in,
                              void* d_out, int out_size, void* d_ws, size_t ws_size,
                              hipStream_t stream) {
    const float* x = (const float*)d_in[0];
    const float* c = (const float*)d_in[1];
    float* out = (float*)d_out;
    float* wsf = (float*)d_ws;                          // 256*2*16 floats = 32 KB
    __bf16* bpk = (__bf16*)((char*)d_ws + 65536);       // 128 chunks * 1 KB = 128 KB

    pack_kernel<<<128, 64, 0, stream>>>(c, bpk);
    dists_mfma<<<dim3(NB, 2), 256, 0, stream>>>(x, bpk, wsf);
    finalize<<<NB, 256, 0, stream>>>(x, wsf, out);
}

// Round 4
// 82.884 us; speedup vs baseline: 1.0076x; 1.0076x over previous
//
#include <hip/hip_runtime.h>
#include <math.h>

// KShape dists via bf16 MFMA. B=256, K=16, SZ=512, D=8.
// corr[b,i,k] = sum_{t,d} xpad[b][(i+t)*8+d] * c[k][t*8+d],  i in [0,1022] (lag s=i-511)
// dists[b,k] = max_i corr / (||x_b|| * k); k=0 -> 0. labels = first argmax.
// out: [0..255]=labels(float), [256..4351]=dists.
//
// R4: one 512-thread block per b (256 blocks = 1/CU). 8 waves x 8 row-tiles
// via 32-slot LDS A-ring (1 ds_read_b128 feeds 8 MFMAs, 4-iter refill
// distance covers LDS latency); B-fragment FIFO depth 8 (~400cy) covers L2
// latency. Norm+dists+labels fused into the epilogue (no finalize kernel).

#define NB 256
#define NK 16
#define NS 512
#define ND 8
#define BAND 1560   // refill prefetch reaches row 128*7+18+4*159 = 1550

typedef __bf16 bf16x8 __attribute__((ext_vector_type(8)));
typedef float floatx4 __attribute__((ext_vector_type(4)));

// ---- pack centers into B-fragment order ----
// Bpk[kc*64 + L][0..8) = bf16( c[n = L&15][ (kc*4 + (L>>4))*8 + j ] )  j=0..7
__global__ void pack_kernel(const float* __restrict__ c, __bf16* __restrict__ bpk)
{
    int kc = blockIdx.x;      // 0..127 chunk of 32 contraction elems
    int L  = threadIdx.x;     // 0..63
    int n = L & 15, quad = L >> 4;
    const float4* src = (const float4*)(c + ((size_t)n * NS + (size_t)(kc * 4 + quad)) * ND);
    float4 a = src[0], b = src[1];
    bf16x8 v;
    v[0] = (__bf16)a.x; v[1] = (__bf16)a.y; v[2] = (__bf16)a.z; v[3] = (__bf16)a.w;
    v[4] = (__bf16)b.x; v[5] = (__bf16)b.y; v[6] = (__bf16)b.z; v[7] = (__bf16)b.w;
    *(bf16x8*)(bpk + ((size_t)kc * 64 + L) * 8) = v;
}

// ---- main: one block = one b; 8 waves x 8 row-tiles = 1024 lag rows ----
__global__ __launch_bounds__(512, 2) void dists_mfma(
    const float* __restrict__ x, const __bf16* __restrict__ bpk, float* __restrict__ out)
{
    __shared__ __align__(16) __bf16 xq[BAND * 8];   // 24.4 KB
    __shared__ float wred[8][16];
    __shared__ float redn[8];
    __shared__ float s_norm;
    __shared__ float dd[16];

    const int tid = threadIdx.x;
    const int b   = blockIdx.x;

    // stage padded x band (bf16) + accumulate sum of squares (f32, for norm)
    float ss = 0.f;
    for (int jj = tid; jj < BAND; jj += 512) {
        bf16x8 v;
        if (jj >= 511 && jj < 1023) {
            const float4* p = (const float4*)(x + ((size_t)b * NS + (size_t)(jj - 511)) * ND);
            float4 a = p[0], bb = p[1];
            ss += a.x * a.x + a.y * a.y + a.z * a.z + a.w * a.w;
            ss += bb.x * bb.x + bb.y * bb.y + bb.z * bb.z + bb.w * bb.w;
            v[0] = (__bf16)a.x;  v[1] = (__bf16)a.y;  v[2] = (__bf16)a.z;  v[3] = (__bf16)a.w;
            v[4] = (__bf16)bb.x; v[5] = (__bf16)bb.y; v[6] = (__bf16)bb.z; v[7] = (__bf16)bb.w;
        } else {
            #pragma unroll
            for (int e = 0; e < 8; ++e) v[e] = (__bf16)0.0f;
        }
        *(bf16x8*)(xq + (size_t)jj * 8) = v;
    }
    #pragma unroll
    for (int off = 32; off; off >>= 1) ss += __shfl_down(ss, off);
    if ((tid & 63) == 0) redn[tid >> 6] = ss;
    __syncthreads();
    if (tid == 0) {
        float t = 0.f;
        #pragma unroll
        for (int i = 0; i < 8; ++i) t += redn[i];
        s_norm = sqrtf(t);
    }

    const int L    = tid & 63;
    const int w    = tid >> 6;     // wave id: rows [128w, 128w+128), tiles rt=0..7
    const int m    = L & 15;       // A row within tile / D col (center id)
    const int quad = L >> 4;

    // A-frag for (rt, kc): 16B at gb + 8*(16rt + 4kc)
    const __bf16* gb = xq + 8 * (128 * w + m + quad);
    const bf16x8* Bp = (const bf16x8*)bpk;

    // ring: Q[(kc + 4rt) & 31] = frag(rt, kc). Init slots = row4 0..31.
    bf16x8 Q[32];
    #pragma unroll
    for (int i = 0; i < 32; ++i) Q[i] = *(const bf16x8*)(gb + 32 * i);

    // B prefetch FIFO, depth 8 (~400cy ahead, covers L2 latency)
    bf16x8 Bv[8];
    #pragma unroll
    for (int i = 0; i < 8; ++i) Bv[i] = Bp[(size_t)i * 64 + L];

    floatx4 acc[8] = {};

    for (int kc0 = 0; kc0 < 128; kc0 += 32) {
        #pragma unroll
        for (int s = 0; s < 32; ++s) {
            const int kc = kc0 + s;
            bf16x8 bcur = Bv[s & 7];
            acc[0] = __builtin_amdgcn_mfma_f32_16x16x32_bf16(Q[(s + 0)  & 31], bcur, acc[0], 0, 0, 0);
            acc[1] = __builtin_amdgcn_mfma_f32_16x16x32_bf16(Q[(s + 4)  & 31], bcur, acc[1], 0, 0, 0);
            acc[2] = __builtin_amdgcn_mfma_f32_16x16x32_bf16(Q[(s + 8)  & 31], bcur, acc[2], 0, 0, 0);
            acc[3] = __builtin_amdgcn_mfma_f32_16x16x32_bf16(Q[(s + 12) & 31], bcur, acc[3], 0, 0, 0);
            acc[4] = __builtin_amdgcn_mfma_f32_16x16x32_bf16(Q[(s + 16) & 31], bcur, acc[4], 0, 0, 0);
            acc[5] = __builtin_amdgcn_mfma_f32_16x16x32_bf16(Q[(s + 20) & 31], bcur, acc[5], 0, 0, 0);
            acc[6] = __builtin_amdgcn_mfma_f32_16x16x32_bf16(Q[(s + 24) & 31], bcur, acc[6], 0, 0, 0);
            acc[7] = __builtin_amdgcn_mfma_f32_16x16x32_bf16(Q[(s + 28) & 31], bcur, acc[7], 0, 0, 0);
            // slot s dead after rt=0 use this iter; refill with row4 = kc+32
            Q[s & 31] = *(const bf16x8*)(gb + 8 * (4 * kc + 128));
            Bv[s & 7] = Bp[(size_t)((kc + 8) & 127) * 64 + L];
        }
    }

    // D layout: col = lane&15 (center), row-in-tile = quad*4 + e.
    // global lag row = 128w + 16rt + 4quad + e; phantom row 1023 excluded.
    float vmax = -INFINITY;
    #pragma unroll
    for (int r = 0; r < 8; ++r) {
        #pragma unroll
        for (int e = 0; e < 4; ++e) {
            bool phantom = (w == 7) & (r == 7) & (quad == 3) & (e == 3);
            vmax = fmaxf(vmax, phantom ? -INFINITY : acc[r][e]);
        }
    }
    vmax = fmaxf(vmax, __shfl_xor(vmax, 16));
    vmax = fmaxf(vmax, __shfl_xor(vmax, 32));
    if (quad == 0) wred[w][m] = vmax;
    __syncthreads();

    if (tid < 16) {
        float mm = wred[0][tid];
        #pragma unroll
        for (int i = 1; i < 8; ++i) mm = fmaxf(mm, wred[i][tid]);
        float denom = s_norm * (float)tid;
        float d = (denom < 1e-9f) ? 0.f : mm / denom;
        dd[tid] = d;
        out[NB + b * NK + tid] = d;
    }
    __syncthreads();
    if (tid == 0) {
        float best = dd[0]; int lab = 0;
        #pragma unroll
        for (int k = 1; k < NK; ++k) if (dd[k] > best) { best = dd[k]; lab = k; }
        out[b] = (float)lab;
    }
}

extern "C" void kernel_launch(void* const* d_in, const int* in_sizes, int n_in,
                              void* d_out, int out_size, void* d_ws, size_t ws_size,
                              hipStream_t stream) {
    const float* x = (const float*)d_in[0];
    const float* c = (const float*)d_in[1];
    float* out = (float*)d_out;
    __bf16* bpk = (__bf16*)d_ws;    // 128 chunks * 1 KB = 128 KB

    pack_kernel<<<128, 64, 0, stream>>>(c, bpk);
    dists_mfma<<<NB, 512, 0, stream>>>(x, bpk, out);
}